// Round 9
// baseline (155.097 us; speedup 1.0000x reference)
//
#include <hip/hip_runtime.h>
#include <hip/hip_bf16.h>
#include <stdint.h>

#define M_DIM 4096
#define N_DIM 4096
#define K_DIM 2048

typedef __bf16 bf16x8 __attribute__((ext_vector_type(8)));
typedef float f32x4 __attribute__((ext_vector_type(4)));
typedef unsigned short u16x8 __attribute__((ext_vector_type(8)));

// Convert BOTH tensors fp32->bf16 with the XOR column-granule swizzle
// (granule g of row r within each 64-col K-tile holds source granule
// g ^ (r&7)) so the forced-linear global_load_lds staging yields a
// bank-conflict-free LDS tile. Block 0 additionally zeroes S.
// R6 lesson: stays a SEPARATE dispatch (fusing into the 128KB-LDS gemm
// kernel starved it of TLP: ~1.4 TB/s, +70us).
// R9 CHANGE: (1) 4 granules/thread, per-block-uniform tensor select
// (blocks 0-1023 -> x, 1024-2047 -> W; no divergence, setup amortized 4x,
// 8 independent 16B loads in flight per thread); (2) __float2bfloat16
// casts instead of manual bit-twiddle RNE so the backend can fuse pairs
// into v_cvt_pk_bf16_f32 (m240: compiler fuses scalar casts; hand-rolled
// bit math defeats the pattern). Same RNE rounding -> identical results.
__global__ void __launch_bounds__(256) cvt_swz_kernel(
    const float* __restrict__ x, const float* __restrict__ w,
    unsigned short* __restrict__ xb, unsigned short* __restrict__ wb,
    float* __restrict__ S) {
  if (blockIdx.x == 0) {
#pragma unroll
    for (int k = 0; k < 16; ++k)
      S[threadIdx.x + k * 256] = 0.f;
  }

  const bool isW = blockIdx.x >= 1024;           // uniform per block
  const float* src = isW ? w : x;
  unsigned short* dst = isW ? wb : xb;
  const int base = (blockIdx.x & 1023) * 1024;   // granule base of this block

#pragma unroll
  for (int it = 0; it < 4; ++it) {
    const int gid = base + it * 256 + threadIdx.x;
    const int row = gid >> 8;        // K/8 = 256 granules per row
    const int cg  = gid & 255;
    const int kt  = cg >> 3;
    const int g   = cg & 7;
    const int sg  = g ^ (row & 7);   // swizzled source granule

    const float4* s4 =
        (const float4*)(src + (size_t)row * K_DIM + kt * 64 + sg * 8);
    float4 f0 = s4[0], f1 = s4[1];
    u16x8 o;
    {
      __hip_bfloat16 h;
      h = __float2bfloat16(f0.x); o[0] = *(unsigned short*)&h;
      h = __float2bfloat16(f0.y); o[1] = *(unsigned short*)&h;
      h = __float2bfloat16(f0.z); o[2] = *(unsigned short*)&h;
      h = __float2bfloat16(f0.w); o[3] = *(unsigned short*)&h;
      h = __float2bfloat16(f1.x); o[4] = *(unsigned short*)&h;
      h = __float2bfloat16(f1.y); o[5] = *(unsigned short*)&h;
      h = __float2bfloat16(f1.z); o[6] = *(unsigned short*)&h;
      h = __float2bfloat16(f1.w); o[7] = *(unsigned short*)&h;
    }
    ((u16x8*)dst)[gid] = o;
  }
}

// ---------------- async global -> LDS, 16B per lane ----------------
__device__ __forceinline__ void gload_lds16(const unsigned short* g, unsigned short* l) {
  __builtin_amdgcn_global_load_lds(
      (const __attribute__((address_space(1))) unsigned int*)g,
      (__attribute__((address_space(3))) unsigned int*)l,
      16, 0, 0);
}

// Stage one 256x64 A-tile + 256x64 B-tile (4 calls each; 512 lanes x 16B
// = 64 rows per call). xg/wg/lA/lB already carry the per-thread offset
// (row tid>>3, col (tid&7)*8  ->  LDS addr = base + tid*16B, the linear
// map global_load_lds requires).
__device__ __forceinline__ void stage_tile(
    const unsigned short* xg, const unsigned short* wg,
    unsigned short* lA, unsigned short* lB, int k0) {
#pragma unroll
  for (int c = 0; c < 4; ++c) {
    gload_lds16(xg + (size_t)(c * 64) * K_DIM + k0, lA + c * 64 * 64);
    gload_lds16(wg + (size_t)(c * 64) * K_DIM + k0, lB + c * 64 * 64);
  }
}

// One K=64 compute step on a staged tile pair — R0's verified MFMA order
// with R8's hoisted tile-invariant LDS byte-offsets (VALUBusy 22.7->18.9%,
// wall-clock-equal to R0; kept as the cleaner form).
// Ledger of refuted attacks on this structure (all HW-measured):
//   R1 8-phase counted-vmcnt  +9.4us total | R3 pinned interleave  +0.7 (neutral)
//   R4 32x32x16 shape        +14.1us total | R6 mega-fusion        +62us
//   R7 ticket-finalize        +8.5us total | R8 offset hoist        neutral
// Timed totals are the only trustworthy comparator (profiled gemm absolutes
// vary 58-103us across sessions at identical wall clock).
__device__ __forceinline__ void compute_tile(
    const char* Ab, const char* Bb,   // byte pointers to this tile's buffers
    const int aoff[2], const int boff[2], f32x4 acc[4][8]) {
#pragma unroll
  for (int ks = 0; ks < 2; ++ks) {
    const char* pa = Ab + aoff[ks];
    const char* pb = Bb + boff[ks];
    bf16x8 af[4], bfr[8];
#pragma unroll
    for (int i = 0; i < 4; ++i)
      af[i]  = *(const bf16x8*)(pa + i * 2048);
#pragma unroll
    for (int i = 0; i < 8; ++i)
      bfr[i] = *(const bf16x8*)(pb + i * 2048);
#pragma unroll
    for (int mi = 0; mi < 4; ++mi)
#pragma unroll
      for (int ni = 0; ni < 8; ++ni)
        acc[mi][ni] = __builtin_amdgcn_mfma_f32_16x16x32_bf16(
            af[mi], bfr[ni], acc[mi][ni], 0, 0, 0);
  }
}

// ---------------- fused GEMM -> clamp -> sum exp(v-10) per row ----------------
// 256x256 block tile, 512 threads = 8 waves, each wave 64x128 (4x8 frags of
// 16x16x32 bf16). DOUBLE-BUFFERED LDS (128 KB dynamic), ONE barrier per
// K-tile: DMA for tile kt+1 issues right after the barrier and stays in
// flight across the whole compute(kt) phase, so the barrier's vmcnt(0)
// drain is ~free.
__global__ void __launch_bounds__(512, 2) gemm_lse_kernel(
    const unsigned short* __restrict__ xb,   // [M][K] bf16, swizzled granules
    const unsigned short* __restrict__ wb,   // [N][K] bf16, swizzled granules
    const float* __restrict__ bias,          // [N]
    float* __restrict__ S) {                 // [M] partial sums of exp(clamp(v)-10)
  extern __shared__ __align__(16) unsigned short lds[];
  const char* ldsb = (const char*)lds;
  // A buffers at bytes 0 / 32768; B buffers at 65536 / 98304.

  const int tid = threadIdx.x;
  const int bm0 = blockIdx.y * 256;
  const int bn0 = blockIdx.x * 256;

  const int wave = tid >> 6, lane = tid & 63;
  const int wr = (wave & 3) * 64;    // wave row offset (0..192)
  const int wc = (wave >> 2) * 128;  // wave col offset (0/128)
  const int lr = lane & 15;
  const int q  = lane >> 4;

  // Tile-invariant per-lane LDS byte offsets (row*128 + swizzled granule*16).
  int aoff[2], boff[2];
#pragma unroll
  for (int ks = 0; ks < 2; ++ks) {
    const int swb = (((ks * 4 + q) ^ (lr & 7)) * 16);
    aoff[ks] = (wr + lr) * 128 + swb;
    boff[ks] = (wc + lr) * 128 + swb;
  }

  f32x4 acc[4][8];
  const f32x4 zero = {0.f, 0.f, 0.f, 0.f};
#pragma unroll
  for (int mi = 0; mi < 4; ++mi)
#pragma unroll
    for (int ni = 0; ni < 8; ++ni)
      acc[mi][ni] = zero;

  const int srow = tid >> 3;        // 0..63
  const int scol = (tid & 7) * 8;

  const unsigned short* xg = xb + (size_t)(bm0 + srow) * K_DIM + scol;
  const unsigned short* wg = wb + (size_t)(bn0 + srow) * K_DIM + scol;
  unsigned short* lA = lds + tid * 8;            // into As0 (+16384 for As1)
  unsigned short* lB = lds + 32768 + tid * 8;    // into Bs0 (+16384 for Bs1)

  stage_tile(xg, wg, lA, lB, 0);                 // prologue: tile 0 -> buf0

  for (int kt = 0; kt < 32; kt += 2) {
    __syncthreads();  // drains this wave's DMA (tile kt, issued a full
                      // compute-phase ago) + syncs: buf1 free to overwrite
    if (kt + 1 < 32)
      stage_tile(xg, wg, lA + 16384, lB + 16384, (kt + 1) * 64);
    compute_tile(ldsb, ldsb + 65536, aoff, boff, acc);

    __syncthreads();  // drains tile kt+1 DMA; buf0 free to overwrite
    if (kt + 2 < 32)
      stage_tile(xg, wg, lA, lB, (kt + 2) * 64);
    compute_tile(ldsb + 32768, ldsb + 98304, aoff, boff, acc);
  }

  // Epilogue: bias + clamp + exp(v-10); reduce across 16 lanes (128 cols);
  // one fire-and-forget atomic per row per wave (32 contributions/row total).
  float bv[8];
#pragma unroll
  for (int ni = 0; ni < 8; ++ni)
    bv[ni] = bias[bn0 + wc + ni * 16 + lr];

#pragma unroll
  for (int mi = 0; mi < 4; ++mi) {
#pragma unroll
    for (int reg = 0; reg < 4; ++reg) {
      float s = 0.f;
#pragma unroll
      for (int ni = 0; ni < 8; ++ni) {
        float v = acc[mi][ni][reg] + bv[ni];  // SCALE_FACTOR*2 == 1.0
        v = fminf(fmaxf(v, -10.f), 10.f);
        s += __expf(v - 10.f);
      }
      s += __shfl_xor(s, 1);
      s += __shfl_xor(s, 2);
      s += __shfl_xor(s, 4);
      s += __shfl_xor(s, 8);
      if (lr == 0)
        atomicAdd(&S[bm0 + wr + mi * 16 + q * 4 + reg], s);
    }
  }
}

// ---------------- finalize: lse = 10 + log(S); mish(lse) ----------------
__global__ void __launch_bounds__(256) finalize_kernel(const float* __restrict__ S,
                                                       float* __restrict__ out) {
  int i = blockIdx.x * blockDim.x + threadIdx.x;
  float lse = 10.0f + logf(S[i]);
  float sp = fmaxf(lse, 0.f) + log1pf(expf(-fabsf(lse)));  // stable softplus
  out[i] = lse * tanhf(sp);
}

extern "C" void kernel_launch(void* const* d_in, const int* in_sizes, int n_in,
                              void* d_out, int out_size, void* d_ws, size_t ws_size,
                              hipStream_t stream) {
  const float* x = (const float*)d_in[0];   // [4096, 2048]
  const float* W = (const float*)d_in[1];   // [4096, 2048]
  const float* b = (const float*)d_in[2];   // [4096]
  float* out = (float*)d_out;               // [4096]

  char* ws = (char*)d_ws;
  float* S = (float*)ws;                                       // 16 KB
  unsigned short* xb = (unsigned short*)(ws + 16384);          // 16 MB
  unsigned short* wb = (unsigned short*)(ws + 16384 + (size_t)M_DIM * K_DIM * 2);

  // 2048 blocks x 256 threads x 4 granules = 2M granules (both tensors).
  cvt_swz_kernel<<<2048, 256, 0, stream>>>(x, W, xb, wb, S);

  // 128 KB dynamic LDS needs the opt-in attribute (idempotent, capture-safe).
  hipFuncSetAttribute((const void*)gemm_lse_kernel,
                      hipFuncAttributeMaxDynamicSharedMemorySize, 131072);
  dim3 grid(N_DIM / 256, M_DIM / 256);  // 16 x 16 = 256 blocks, 1/CU
  gemm_lse_kernel<<<grid, 512, 131072, stream>>>(xb, wb, b, S);

  finalize_kernel<<<M_DIM / 256, 256, 0, stream>>>(S, out);
}